// Round 10
// baseline (3681.734 us; speedup 1.0000x reference)
//
#include <hip/hip_runtime.h>
#include <stdint.h>

#define TFAC 0.05f
#define BM 256
#define BN 256
#define BK 64
#define XCLIP 6.0f
#define SX (XCLIP / 127.0f)

typedef __attribute__((ext_vector_type(4))) int i32x4;

#define AS1(p) ((const __attribute__((address_space(1))) void*)(p))
#define AS3(p) ((__attribute__((address_space(3))) void*)(p))

static __device__ __forceinline__ unsigned pack4(int b0, int b1, int b2, int b3) {
  return (unsigned)(unsigned char)b0 | ((unsigned)(unsigned char)b1 << 8) |
         ((unsigned)(unsigned char)b2 << 16) | ((unsigned)(unsigned char)b3 << 24);
}

// ---------------- weight quantization -> int8 ternary + f32 scale ----------------
__global__ __launch_bounds__(256) void quant_kernel(
    const float* __restrict__ W, unsigned* __restrict__ T,
    float* __restrict__ scale, int IN) {
  const int row = blockIdx.x;
  const int t = threadIdx.x;
  const float4* wr = reinterpret_cast<const float4*>(W + (size_t)row * IN);

  float4 v[4];
  float s = 0.f;
#pragma unroll
  for (int i = 0; i < 4; ++i) {
    v[i] = wr[i * 256 + t];
    s += fabsf(v[i].x) + fabsf(v[i].y) + fabsf(v[i].z) + fabsf(v[i].w);
  }
#pragma unroll
  for (int off = 1; off < 64; off <<= 1) s += __shfl_xor(s, off);
  __shared__ float red[4];
  if ((t & 63) == 0) red[t >> 6] = s;
  __syncthreads();
  const float tot = red[0] + red[1] + red[2] + red[3];
  const float thr = TFAC * tot / (float)IN;

  float cnt = 0.f, ms = 0.f;
  unsigned* trow = T + (size_t)row * (IN / 4);
#pragma unroll
  for (int i = 0; i < 4; ++i) {
    float e[4] = {v[i].x, v[i].y, v[i].z, v[i].w};
    int o[4];
#pragma unroll
    for (int j = 0; j < 4; ++j) {
      const float a = fabsf(e[j]);
      const bool m = a > thr;
      cnt += m ? 1.f : 0.f;
      ms += m ? a : 0.f;
      o[j] = m ? (e[j] > 0.f ? 1 : -1) : 0;
    }
    trow[i * 256 + t] = pack4(o[0], o[1], o[2], o[3]);
  }
#pragma unroll
  for (int off = 1; off < 64; off <<= 1) {
    cnt += __shfl_xor(cnt, off);
    ms += __shfl_xor(ms, off);
  }
  __shared__ float rc[4], rm[4];
  if ((t & 63) == 0) { rc[t >> 6] = cnt; rm[t >> 6] = ms; }
  __syncthreads();
  if (t == 0) {
    const float c = rc[0] + rc[1] + rc[2] + rc[3];
    const float m = rm[0] + rm[1] + rm[2] + rm[3];
    scale[row] = m / fmaxf(c, 1.f);
  }
}

// ---------------- x f32 -> i8 (global scale) ----------------
__global__ __launch_bounds__(256) void cvt_kernel(
    const float* __restrict__ X, unsigned* __restrict__ X8, size_t n4) {
  const size_t base = ((size_t)blockIdx.x * 256) * 4;
  const int t = threadIdx.x;
  const float inv = 127.0f / XCLIP;
#pragma unroll
  for (int i = 0; i < 4; ++i) {
    const size_t idx = base + (size_t)i * 256 + t;
    if (idx >= n4) return;
    const float4 a = reinterpret_cast<const float4*>(X)[idx];
    int b[4];
    b[0] = (int)rintf(fminf(fmaxf(a.x * inv, -127.f), 127.f));
    b[1] = (int)rintf(fminf(fmaxf(a.y * inv, -127.f), 127.f));
    b[2] = (int)rintf(fminf(fmaxf(a.z * inv, -127.f), 127.f));
    b[3] = (int)rintf(fminf(fmaxf(a.w * inv, -127.f), 127.f));
    X8[idx] = pack4(b[0], b[1], b[2], b[3]);
  }
}

// --- 256x256 i8 NT GEMM, BK=64, 4 waves of 128x128, dbuf, 2 blocks/CU ---
// LDS packing (r9-proven): global row r (64 B of K) at LDS row r>>1, half r&1,
// XOR-swizzled with (r>>1)&7 -> <=2-way conflicts on b128 reads, 128 B pitch.
static __device__ __forceinline__ i32x4 lds_rd(
    const signed char* buf, int grow, int lg) {
  const int rp = grow >> 1;
  const int c = (((grow & 1) << 2) + lg) ^ (rp & 7);
  return *reinterpret_cast<const i32x4*>(buf + rp * 128 + c * 16);
}

__global__ __launch_bounds__(256, 2) void gemm_kernel(
    const signed char* __restrict__ A,    // x i8 [M][K]
    const signed char* __restrict__ Bt,   // tern i8 [N][K]
    const float* __restrict__ scale,      // [N]
    const float* __restrict__ bias,       // [N]
    float* __restrict__ C,                // [M][N]
    int M, int N, int K) {
  __shared__ signed char lds[65536];
  signed char* const sA0 = lds;           // 16 KiB A tile (256 rows x 64 B)
  signed char* const sA1 = lds + 16384;
  signed char* const sB0 = lds + 32768;   // 16 KiB B tile (256 rows x 64 B)
  signed char* const sB1 = lds + 49152;

  const int tid = (int)threadIdx.x;
  const int lane = tid & 63;
  const int w = tid >> 6;   // 0..3
  const int wm = w >> 1;    // 0..1
  const int wn = w & 1;     // 0..1
  const int lr = lane & 15;
  const int lg = lane >> 4;

  // bijective XCD band walk: nwg = 32*64 = 2048
  const int nbm = M / BM;             // 32
  const int bid = (int)blockIdx.x;
  const int xcd = bid & 7;
  const int j = bid >> 3;             // 0..255
  const int bm = j >> 3;              // 0..31
  const int bn = xcd * 8 + (j & 7);   // 0..63
  const size_t rowA0 = (size_t)bm * BM;
  const size_t rowB0 = (size_t)bn * BN;
  (void)nbm;

  const int NKT = K / BK;

  // stage addressing: chunk ci (0..1023 per matrix) -> LDS offset ci*16;
  // swizzled source chunk sc = (ci&7)^((ci>>3)&7), global row 2*(ci>>3)+(sc>>2),
  // k-byte (sc&3)*16. 256 threads x 4 chunks each per matrix.
  const signed char* pA[4];
  const signed char* pB[4];
  int dL[4];
#pragma unroll
  for (int i = 0; i < 4; ++i) {
    const int ci = tid + 256 * i;
    const int sc = (ci & 7) ^ ((ci >> 3) & 7);
    const size_t gr = (size_t)(2 * (ci >> 3) + (sc >> 2));
    const int kb = (sc & 3) * 16;
    pA[i] = A + (rowA0 + gr) * (size_t)K + kb;
    pB[i] = Bt + (rowB0 + gr) * (size_t)K + kb;
    dL[i] = ci * 16;
  }

#define STAGE(BA, BB, KOFF)                                                    \
  _Pragma("unroll") for (int i = 0; i < 4; ++i) {                              \
    __builtin_amdgcn_global_load_lds(AS1(pA[i] + (KOFF)), AS3(BA + dL[i]), 16, 0, 0); \
    __builtin_amdgcn_global_load_lds(AS1(pB[i] + (KOFF)), AS3(BB + dL[i]), 16, 0, 0); \
  }

  i32x4 acc[8][8] = {};

  // prologue: tile 0 into buffer 0
  STAGE(sA0, sB0, 0)
  asm volatile("s_waitcnt vmcnt(0)" ::: "memory");
  __builtin_amdgcn_s_barrier();

  for (int kt = 0; kt < NKT; ++kt) {
    const bool odd = (kt & 1) != 0;
    const signed char* sa = odd ? sA1 : sA0;
    const signed char* sb = odd ? sB1 : sB0;
    signed char* na = odd ? sA0 : sA1;
    signed char* nb = odd ? sB0 : sB1;

    if (kt + 1 < NKT) {
      const int koff = (kt + 1) * BK;
      STAGE(na, nb, koff)
    }

    i32x4 ar[8], br[8];
#pragma unroll
    for (int f = 0; f < 8; ++f) ar[f] = lds_rd(sa, wm * 128 + f * 16 + lr, lg);
#pragma unroll
    for (int g = 0; g < 8; ++g) br[g] = lds_rd(sb, wn * 128 + g * 16 + lr, lg);

    __builtin_amdgcn_s_setprio(1);
#pragma unroll
    for (int f = 0; f < 8; ++f)
#pragma unroll
      for (int g = 0; g < 8; ++g)
        acc[f][g] = __builtin_amdgcn_mfma_i32_16x16x64_i8(
            ar[f], br[g], acc[f][g], 0, 0, 0);
    __builtin_amdgcn_s_setprio(0);

    // explicit drains (r8 race lesson): reads of buf[kt&1] done before overwrite;
    // DMA into buf[(kt+1)&1] landed before it is read.
    asm volatile("s_waitcnt lgkmcnt(0)" ::: "memory");
    asm volatile("s_waitcnt vmcnt(0)" ::: "memory");
    __builtin_amdgcn_s_barrier();
  }

  // ---- epilogue: y = acc * (SX*scale[col]) + bias[col] ----
#pragma unroll
  for (int g = 0; g < 8; ++g) {
    const int col = (int)rowB0 + wn * 128 + g * 16 + lr;
    const float sc = SX * scale[col];
    const float bs = bias[col];
#pragma unroll
    for (int f = 0; f < 8; ++f) {
      const size_t r0 = rowA0 + (size_t)(wm * 128 + f * 16 + lg * 4);
#pragma unroll
      for (int rr = 0; rr < 4; ++rr) {
        __builtin_nontemporal_store((float)acc[f][g][rr] * sc + bs,
                                    &C[(r0 + rr) * (size_t)N + col]);
      }
    }
  }
#undef STAGE
}

extern "C" void kernel_launch(void* const* d_in, const int* in_sizes, int n_in,
                              void* d_out, int out_size, void* d_ws, size_t ws_size,
                              hipStream_t stream) {
  (void)n_in; (void)out_size; (void)ws_size;
  const float* x = (const float*)d_in[0];
  const float* wgt = (const float*)d_in[1];
  const float* bias = (const float*)d_in[2];
  float* y = (float*)d_out;

  const int OUT = in_sizes[2];
  const int IN = in_sizes[1] / OUT;
  const int B = in_sizes[0] / IN;

  signed char* tern = (signed char*)d_ws;
  signed char* xb = (signed char*)((char*)d_ws + (size_t)OUT * IN);
  float* scale = (float*)((char*)d_ws + (size_t)OUT * IN + (size_t)B * IN);

  quant_kernel<<<OUT, 256, 0, stream>>>(wgt, (unsigned*)tern, scale, IN);

  const size_t n4 = (size_t)B * IN / 4;
  cvt_kernel<<<(unsigned)((n4 + 1023) / 1024), 256, 0, stream>>>(x, (unsigned*)xb, n4);

  gemm_kernel<<<(B / BM) * (OUT / BN), 256, 0, stream>>>(xb, tern, scale, bias, y, B, OUT, IN);
}

// Round 11
// 649.959 us; speedup vs baseline: 5.6646x; 5.6646x over previous
//
#include <hip/hip_runtime.h>
#include <stdint.h>

#define TFAC 0.05f
#define BM 256
#define BN 128
#define BK 64
#define XCLIP 6.0f
#define SX (XCLIP / 127.0f)

typedef __attribute__((ext_vector_type(4))) int i32x4;

#define AS1(p) ((const __attribute__((address_space(1))) void*)(p))
#define AS3(p) ((__attribute__((address_space(3))) void*)(p))
#define SB0() __builtin_amdgcn_sched_barrier(0)

static __device__ __forceinline__ unsigned pack4(int b0, int b1, int b2, int b3) {
  return (unsigned)(unsigned char)b0 | ((unsigned)(unsigned char)b1 << 8) |
         ((unsigned)(unsigned char)b2 << 16) | ((unsigned)(unsigned char)b3 << 24);
}

// ---------------- weight quantization -> int8 ternary + f32 scale ----------------
__global__ __launch_bounds__(256) void quant_kernel(
    const float* __restrict__ W, unsigned* __restrict__ T,
    float* __restrict__ scale, int IN) {
  const int row = blockIdx.x;
  const int t = threadIdx.x;
  const float4* wr = reinterpret_cast<const float4*>(W + (size_t)row * IN);

  float4 v[4];
  float s = 0.f;
#pragma unroll
  for (int i = 0; i < 4; ++i) {
    v[i] = wr[i * 256 + t];
    s += fabsf(v[i].x) + fabsf(v[i].y) + fabsf(v[i].z) + fabsf(v[i].w);
  }
#pragma unroll
  for (int off = 1; off < 64; off <<= 1) s += __shfl_xor(s, off);
  __shared__ float red[4];
  if ((t & 63) == 0) red[t >> 6] = s;
  __syncthreads();
  const float tot = red[0] + red[1] + red[2] + red[3];
  const float thr = TFAC * tot / (float)IN;

  float cnt = 0.f, ms = 0.f;
  unsigned* trow = T + (size_t)row * (IN / 4);
#pragma unroll
  for (int i = 0; i < 4; ++i) {
    float e[4] = {v[i].x, v[i].y, v[i].z, v[i].w};
    int o[4];
#pragma unroll
    for (int j = 0; j < 4; ++j) {
      const float a = fabsf(e[j]);
      const bool m = a > thr;
      cnt += m ? 1.f : 0.f;
      ms += m ? a : 0.f;
      o[j] = m ? (e[j] > 0.f ? 1 : -1) : 0;
    }
    trow[i * 256 + t] = pack4(o[0], o[1], o[2], o[3]);
  }
#pragma unroll
  for (int off = 1; off < 64; off <<= 1) {
    cnt += __shfl_xor(cnt, off);
    ms += __shfl_xor(ms, off);
  }
  __shared__ float rc[4], rm[4];
  if ((t & 63) == 0) { rc[t >> 6] = cnt; rm[t >> 6] = ms; }
  __syncthreads();
  if (t == 0) {
    const float c = rc[0] + rc[1] + rc[2] + rc[3];
    const float m = rm[0] + rm[1] + rm[2] + rm[3];
    scale[row] = m / fmaxf(c, 1.f);
  }
}

// ---------------- x f32 -> i8 (global scale) ----------------
__global__ __launch_bounds__(256) void cvt_kernel(
    const float* __restrict__ X, unsigned* __restrict__ X8, size_t n4) {
  const size_t base = ((size_t)blockIdx.x * 256) * 4;
  const int t = threadIdx.x;
  const float inv = 127.0f / XCLIP;
#pragma unroll
  for (int i = 0; i < 4; ++i) {
    const size_t idx = base + (size_t)i * 256 + t;
    if (idx >= n4) return;
    const float4 a = reinterpret_cast<const float4*>(X)[idx];
    int b[4];
    b[0] = (int)rintf(fminf(fmaxf(a.x * inv, -127.f), 127.f));
    b[1] = (int)rintf(fminf(fmaxf(a.y * inv, -127.f), 127.f));
    b[2] = (int)rintf(fminf(fmaxf(a.z * inv, -127.f), 127.f));
    b[3] = (int)rintf(fminf(fmaxf(a.w * inv, -127.f), 127.f));
    X8[idx] = pack4(b[0], b[1], b[2], b[3]);
  }
}

// ---- 256x128 i8 NT GEMM: LDS triple-buffer, frag double-buffer (WAR-free),
// ---- counted vmcnt, one barrier/tile, 2 blocks/CU, 4 waves of 128x64 ----
static __device__ __forceinline__ i32x4 lds_rd(
    const signed char* buf, int grow, int lg) {
  const int rp = grow >> 1;
  const int c = (((grow & 1) << 2) + lg) ^ (rp & 7);
  return *reinterpret_cast<const i32x4*>(buf + rp * 128 + c * 16);
}

__global__ __launch_bounds__(256, 2) void gemm_kernel(
    const signed char* __restrict__ A,    // x i8 [M][K]
    const signed char* __restrict__ Bt,   // tern i8 [N][K]
    const float* __restrict__ scale,      // [N]
    const float* __restrict__ bias,       // [N]
    float* __restrict__ C,                // [M][N]
    int M, int N, int K) {
  __shared__ signed char lds[3 * 24576];  // slot = A 16KB + B 8KB; 72 KiB total

  const int tid = (int)threadIdx.x;
  const int lane = tid & 63;
  const int w = tid >> 6;   // 0..3
  const int wm = w >> 1;    // 0..1 : 128-row half
  const int wn = w & 1;     // 0..1 : 64-col half
  const int lr = lane & 15;
  const int lg = lane >> 4;

  // XCD swizzle with intra-XCD 8-wide bn bands (r9-verified, bijective)
  const int nbm = M / BM;             // 32
  const int nbn = N / BN;             // 128
  const int nwg = nbm * nbn;          // 4096
  const int jpx = nwg >> 3;           // 512
  const int rows8 = nbm * 8;          // 256
  const int nband = jpx / rows8;      // 2
  const int bid = (int)blockIdx.x;
  const int xcd = bid & 7;
  const int j = bid >> 3;
  const int band = j / rows8;
  const int r = j % rows8;
  const int bm = r >> 3;
  const int bn = (xcd * nband + band) * 8 + (r & 7);
  const size_t rowA0 = (size_t)bm * BM;
  const size_t rowB0 = (size_t)bn * BN;

  const int NKT = K / BK;             // 64

  // stage addressing (r9-proven formulas): LDS chunk ci -> row-pair ci>>3,
  // chunk ci&7; swizzled source chunk sc=(ci&7)^((ci>>3)&7) -> global row
  // 2*(ci>>3)+(sc>>2), k-byte (sc&3)*16. Strides: ci+256 -> +64 global rows.
  const int ci = tid;
  const int sc = (ci & 7) ^ ((ci >> 3) & 7);
  const size_t gr = (size_t)(2 * (ci >> 3) + (sc >> 2));
  const int kb = (sc & 3) * 16;
  const size_t strideRow = (size_t)64 * (size_t)K;
  const signed char* pA0 = A + (rowA0 + gr) * (size_t)K + kb;
  const signed char* pB0 = Bt + (rowB0 + gr) * (size_t)K + kb;
  const int d0 = ci * 16;

#define STAGE(SLOT, KOFF)                                                      \
  do {                                                                         \
    signed char* _sa = (SLOT);                                                 \
    signed char* _sb = (SLOT) + 16384;                                         \
    _Pragma("unroll") for (int i = 0; i < 4; ++i)                              \
        __builtin_amdgcn_global_load_lds(                                      \
            AS1(pA0 + (size_t)i * strideRow + (KOFF)),                         \
            AS3(_sa + d0 + i * 4096), 16, 0, 0);                               \
    _Pragma("unroll") for (int i = 0; i < 2; ++i)                              \
        __builtin_amdgcn_global_load_lds(                                      \
            AS1(pB0 + (size_t)i * strideRow + (KOFF)),                         \
            AS3(_sb + d0 + i * 4096), 16, 0, 0);                               \
  } while (0)

#define RDF(AR, BR, SLOT)                                                      \
  do {                                                                         \
    const signed char* _sa = (SLOT);                                           \
    const signed char* _sb = (SLOT) + 16384;                                   \
    _Pragma("unroll") for (int f = 0; f < 8; ++f)                              \
        AR[f] = lds_rd(_sa, wm * 128 + f * 16 + lr, lg);                       \
    _Pragma("unroll") for (int g = 0; g < 4; ++g)                              \
        BR[g] = lds_rd(_sb, wn * 64 + g * 16 + lr, lg);                        \
  } while (0)

#define MM(AR, BR)                                                             \
  __builtin_amdgcn_s_setprio(1);                                               \
  _Pragma("unroll") for (int f = 0; f < 8; ++f)                                \
  _Pragma("unroll") for (int g = 0; g < 4; ++g)                                \
      acc[f][g] = __builtin_amdgcn_mfma_i32_16x16x64_i8(                       \
          AR[f], BR[g], acc[f][g], 0, 0, 0);                                   \
  __builtin_amdgcn_s_setprio(0);                                               \
  SB0();

  // ITER(kt): [frags(kt) ready] MFMA(kt) | stage slot(kt+2) | vmcnt(6): slot
  // (kt+1) landed | barrier | read frags(kt+1) into the OTHER frag buffer
  // (no WAR vs queued MFMAs -> reads drain on LDS pipe under matrix pipe).
#define ITER(SNXT, SSTG, ARc, BRc, ARn, BRn)                                   \
  do {                                                                         \
    asm volatile("s_waitcnt lgkmcnt(0)" ::: "memory");                         \
    SB0();                                                                     \
    MM(ARc, BRc)                                                               \
    {                                                                          \
      const int _kk = kk2 < NKT ? kk2 : NKT - 1;                               \
      STAGE(SSTG, (size_t)_kk * BK);                                           \
    }                                                                          \
    SB0();                                                                     \
    asm volatile("s_waitcnt vmcnt(6)" ::: "memory");                           \
    __builtin_amdgcn_s_barrier();                                              \
    RDF(ARn, BRn, SNXT);                                                       \
    SB0();                                                                     \
    ++kk2;                                                                     \
  } while (0)

  i32x4 acc[8][4] = {};
  i32x4 arA[8], brA[4], arB[8], brB[4];

  signed char* s0 = lds;
  signed char* s1 = lds + 24576;
  signed char* s2 = lds + 49152;

  // prologue: stage tiles 0,1; wait tile 0; preload frags(0) into buf A
  STAGE(s0, 0);
  STAGE(s1, (size_t)BK);
  int kk2 = 2;
  asm volatile("s_waitcnt vmcnt(6)" ::: "memory");
  __builtin_amdgcn_s_barrier();
  RDF(arA, brA, s0);
  SB0();

  signed char* sC = s0;  // slot kt%3 (idle this iter)
  signed char* sN = s1;  // slot (kt+1)%3 (read this iter)
  signed char* sS = s2;  // slot (kt+2)%3 (staged this iter)
  for (int kt = 0; kt < NKT; kt += 2) {
    ITER(sN, sS, arA, brA, arB, brB);
    ITER(sS, sC, arB, brB, arA, brA);
    signed char* t = sC; sC = sS; sS = sN; sN = t;  // advance roles by 2
  }

  // ---- epilogue: y = acc * (SX*scale[col]) + bias[col] ----
#pragma unroll
  for (int g = 0; g < 4; ++g) {
    const int col = (int)rowB0 + wn * 64 + g * 16 + lr;
    const float scv = SX * scale[col];
    const float bs = bias[col];
#pragma unroll
    for (int f = 0; f < 8; ++f) {
      const size_t r0 = rowA0 + (size_t)(wm * 128 + f * 16 + lg * 4);
#pragma unroll
      for (int rr = 0; rr < 4; ++rr) {
        __builtin_nontemporal_store((float)acc[f][g][rr] * scv + bs,
                                    &C[(r0 + rr) * (size_t)N + col]);
      }
    }
  }
#undef STAGE
#undef RDF
#undef MM
#undef ITER
}

extern "C" void kernel_launch(void* const* d_in, const int* in_sizes, int n_in,
                              void* d_out, int out_size, void* d_ws, size_t ws_size,
                              hipStream_t stream) {
  (void)n_in; (void)out_size; (void)ws_size;
  const float* x = (const float*)d_in[0];
  const float* wgt = (const float*)d_in[1];
  const float* bias = (const float*)d_in[2];
  float* y = (float*)d_out;

  const int OUT = in_sizes[2];
  const int IN = in_sizes[1] / OUT;
  const int B = in_sizes[0] / IN;

  signed char* tern = (signed char*)d_ws;
  signed char* xb = (signed char*)((char*)d_ws + (size_t)OUT * IN);
  float* scale = (float*)((char*)d_ws + (size_t)OUT * IN + (size_t)B * IN);

  quant_kernel<<<OUT, 256, 0, stream>>>(wgt, (unsigned*)tern, scale, IN);

  const size_t n4 = (size_t)B * IN / 4;
  cvt_kernel<<<(unsigned)((n4 + 1023) / 1024), 256, 0, stream>>>(x, (unsigned*)xb, n4);

  gemm_kernel<<<(B / BM) * (OUT / BN), 256, 0, stream>>>(xb, tern, scale, bias, y, B, OUT, IN);
}